// Round 2
// baseline (216.124 us; speedup 1.0000x reference)
//
#include <hip/hip_runtime.h>

// Conv 3x3 VALID + ReLU over 262144 independent 16x8 fp32 images.
// Memory-bound: 128 MiB in + 84 MiB out => ~35us floor @ 6.3 TB/s.
// Strategy: LDS-stage input AND output so all global traffic is coalesced
// float4. 4 threads per image; outputs kept in statically-indexed registers.

#define BLOCK 256
#define IPB   64            // images per block (4 threads / image)
#define STRIDE 132          // LDS floats per image: 16B-aligned, bank-balanced
#define NIMG_TOTAL (4096 * 64)

__global__ __launch_bounds__(BLOCK, 4) void conv3x3_relu_kernel(
    const float* __restrict__ x,
    const float* __restrict__ kern,
    float* __restrict__ out)
{
    __shared__ float s[IPB * STRIDE];   // 33792 B; reused for output staging

    const int tid = threadIdx.x;
    const long long img0 = (long long)blockIdx.x * IPB;

    const float k00 = kern[0], k01 = kern[1], k02 = kern[2];
    const float k10 = kern[3], k11 = kern[4], k12 = kern[5];
    const float k20 = kern[6], k21 = kern[7], k22 = kern[8];

    // ---- stage 64 images into LDS: 2048 coalesced float4 loads ----
    const float4* src = reinterpret_cast<const float4*>(x + img0 * 128);
    #pragma unroll
    for (int it = 0; it < 8; ++it) {
        const int f    = it * BLOCK + tid;   // 0..2047
        const int img  = f >> 5;             // 32 float4s per image
        const int off4 = f & 31;
        const float4 v = src[f];
        *reinterpret_cast<float4*>(&s[img * STRIDE + off4 * 4]) = v;
    }
    __syncthreads();

    // ---- compute: 4 threads / image, output-row split {4,4,3,3} ----
    const int img  = tid >> 2;
    const int tq   = tid & 3;
    const int rs   = (tq < 2) ? (tq * 4) : (8 + (tq - 2) * 3);
    const int rcnt = (tq < 2) ? 4 : 3;
    const float* ip = &s[img * STRIDE];

    float acc[4][6];   // statically indexed only -> stays in VGPRs
    #pragma unroll
    for (int rr = 0; rr < 4; ++rr) {
        if (rr < rcnt) {
            const int r = rs + rr;
            float w0[8], w1[8], w2[8];
            *reinterpret_cast<float4*>(&w0[0]) = *reinterpret_cast<const float4*>(ip + r * 8);
            *reinterpret_cast<float4*>(&w0[4]) = *reinterpret_cast<const float4*>(ip + r * 8 + 4);
            *reinterpret_cast<float4*>(&w1[0]) = *reinterpret_cast<const float4*>(ip + r * 8 + 8);
            *reinterpret_cast<float4*>(&w1[4]) = *reinterpret_cast<const float4*>(ip + r * 8 + 12);
            *reinterpret_cast<float4*>(&w2[0]) = *reinterpret_cast<const float4*>(ip + r * 8 + 16);
            *reinterpret_cast<float4*>(&w2[4]) = *reinterpret_cast<const float4*>(ip + r * 8 + 20);
            #pragma unroll
            for (int c = 0; c < 6; ++c) {
                float a = w0[c] * k00 + w0[c + 1] * k01 + w0[c + 2] * k02
                        + w1[c] * k10 + w1[c + 1] * k11 + w1[c + 2] * k12
                        + w2[c] * k20 + w2[c + 1] * k21 + w2[c + 2] * k22;
                acc[rr][c] = fmaxf(a, 0.0f);
            }
        }
    }
    __syncthreads();   // all reads of s done before we overwrite it

    // ---- write outputs into LDS (reuse s): 64 imgs * 84 floats ----
    // All offsets img*84 + r*6 are even -> float2 (ds_write_b64) legal.
    #pragma unroll
    for (int rr = 0; rr < 4; ++rr) {
        if (rr < rcnt) {
            float* op = &s[img * 84 + (rs + rr) * 6];
            *reinterpret_cast<float2*>(op)     = make_float2(acc[rr][0], acc[rr][1]);
            *reinterpret_cast<float2*>(op + 2) = make_float2(acc[rr][2], acc[rr][3]);
            *reinterpret_cast<float2*>(op + 4) = make_float2(acc[rr][4], acc[rr][5]);
        }
    }
    __syncthreads();

    // ---- coalesced store: 5376 floats = 1344 float4 ----
    float4* dst = reinterpret_cast<float4*>(out + img0 * 84);
    const float4* s4 = reinterpret_cast<const float4*>(s);
    #pragma unroll
    for (int it = 0; it < 6; ++it) {
        const int f = it * BLOCK + tid;
        if (f < (IPB * 84) / 4) dst[f] = s4[f];
    }
}

extern "C" void kernel_launch(void* const* d_in, const int* in_sizes, int n_in,
                              void* d_out, int out_size, void* d_ws, size_t ws_size,
                              hipStream_t stream) {
    const float* x    = (const float*)d_in[0];
    const float* kern = (const float*)d_in[1];
    float* out        = (float*)d_out;
    const int nblocks = NIMG_TOTAL / IPB;   // 4096
    conv3x3_relu_kernel<<<nblocks, BLOCK, 0, stream>>>(x, kern, out);
}